// Round 25
// baseline (982.765 us; speedup 1.0000x reference)
//
#include <hip/hip_runtime.h>
#include <hip/hip_bf16.h>

typedef __bf16 v8bf  __attribute__((ext_vector_type(8)));
typedef __bf16 v4bf  __attribute__((ext_vector_type(4)));
typedef float  f32x4 __attribute__((ext_vector_type(4)));
typedef float  f32x8 __attribute__((ext_vector_type(8)));

#define TOKENS 50176
#define CDIM   576
#define NHEAD  18
#define QKVD   1728

// async global->LDS, 16B per lane; LDS dest = wave-uniform base + lane*16
__device__ __forceinline__ void gld16(const __bf16* g, __bf16* l)
{
    __builtin_amdgcn_global_load_lds(
        (const __attribute__((address_space(1))) void*)g,
        (__attribute__((address_space(3))) void*)l,
        16, 0, 0);
}

// exact-GELU via Abramowitz-Stegun 7.1.26 erf (|err| <= 1.5e-7, below bf16 eps)
__device__ __forceinline__ float fast_gelu(float x)
{
    const float z  = x * 0.70710678118654752f;
    const float az = fabsf(z);
    const float t  = __frcp_rn(1.0f + 0.3275911f * az);
    float p = 1.061405429f;
    p = p * t - 1.453152027f;
    p = p * t + 1.421413741f;
    p = p * t - 0.284496736f;
    p = p * t + 0.254829592f;
    const float e   = __expf(-z * z);
    float erfv = 1.0f - p * t * e;
    erfv = copysignf(erfv, z);
    return 0.5f * x * (1.0f + erfv);
}

// ---- fused f32->bf16 cast of all 4 GEMM weights (dests contiguous in ws) ----
__global__ __launch_bounds__(256)
void cast4_kernel(const float* __restrict__ s0, const float* __restrict__ s1,
                  const float* __restrict__ s2, const float* __restrict__ s3,
                  __bf16* __restrict__ dst)
{
    const size_t i = ((size_t)blockIdx.x * 256 + threadIdx.x) * 4;
    constexpr size_t n0 = (size_t)QKVD * CDIM;            // 995328
    constexpr size_t n1 = n0 + (size_t)CDIM * CDIM;       // +331776
    constexpr size_t n2 = n1 + (size_t)2304 * CDIM;       // +1327104
    const float* s; size_t off;
    if (i < n0)      { s = s0; off = i; }
    else if (i < n1) { s = s1; off = i - n0; }
    else if (i < n2) { s = s2; off = i - n1; }
    else             { s = s3; off = i - n2; }
    f32x4 v = *(const f32x4*)&s[off];
    v4bf o;
#pragma unroll
    for (int j = 0; j < 4; ++j) o[j] = (__bf16)v[j];
    *(v4bf*)&dst[i] = o;
}

// ------- conv weight prep: fold BN scale into weights, make [9][576] bf16 -------
__global__ __launch_bounds__(64)
void conv_prep(const float* __restrict__ w, const float* __restrict__ bg,
               const float* __restrict__ bb, const float* __restrict__ bm,
               const float* __restrict__ bv, __bf16* __restrict__ wt,
               float* __restrict__ bias2)
{
    const int c = blockIdx.x * 64 + threadIdx.x;   // 576
    const float inv = rsqrtf(bv[c] + 1e-5f) * bg[c];
#pragma unroll
    for (int t = 0; t < 9; ++t) wt[t * CDIM + c] = (__bf16)(w[c * 9 + t] * inv);
    bias2[c] = bb[c] - bm[c] * inv;
}

// ---------------- LayerNorm (LN_a): one wave per token, f32 in, bf16 out ----
__global__ __launch_bounds__(256)
void ln_kernel(const float* __restrict__ x, const float* __restrict__ g,
               const float* __restrict__ b, __bf16* __restrict__ out)
{
    const int lane = threadIdx.x & 63;
    const int wid  = threadIdx.x >> 6;
    const size_t t = (size_t)blockIdx.x * 4 + wid;
    const float* row = x + t * CDIM;

    float v[16];
    float sum = 0.f, sq = 0.f;
    {
        f32x8 d0 = *(const f32x8*)&row[(size_t)lane * 8];
#pragma unroll
        for (int j = 0; j < 8; ++j) { float f = d0[j]; v[j] = f; sum += f; sq += f * f; }
    }
    if (lane < 8) {
        f32x8 d1 = *(const f32x8*)&row[(size_t)(lane + 64) * 8];
#pragma unroll
        for (int j = 0; j < 8; ++j) { float f = d1[j]; v[8 + j] = f; sum += f; sq += f * f; }
    }
#pragma unroll
    for (int o = 32; o >= 1; o >>= 1) {
        sum += __shfl_xor(sum, o, 64);
        sq  += __shfl_xor(sq,  o, 64);
    }
    const float mean = sum * (1.0f / CDIM);
    const float rstd = rsqrtf(sq * (1.0f / CDIM) - mean * mean + 1e-5f);

    {
        int c0 = lane * 8;
        v8bf o0;
#pragma unroll
        for (int j = 0; j < 8; ++j)
            o0[j] = (__bf16)((v[j] - mean) * rstd * g[c0 + j] + b[c0 + j]);
        *(v8bf*)&out[t * CDIM + c0] = o0;
    }
    if (lane < 8) {
        int c0 = (lane + 64) * 8;
        v8bf o1;
#pragma unroll
        for (int j = 0; j < 8; ++j)
            o1[j] = (__bf16)((v[8 + j] - mean) * rstd * g[c0 + j] + b[c0 + j]);
        *(v8bf*)&out[t * CDIM + c0] = o1;
    }
}

// ------- GEMM (big-tile; best for qkv/proj/fc2): r9 schedule, 512 thr ------
// Tile 256x192, BK=32, 8 waves (2M x 4N), ring-4 LDS 112 KB, stage-ahead-2,
// counted per-wave vmcnt. Subtiled 1KB LDS cells (16 rows x 32 k,
// lane-linear): conflict-free b128, linear gld16 dest.
// EPI: 0 = none, 1 = += add[M][N], 2 = exact GELU
template<int EPI, typename OutT, typename AddT>
__global__ __launch_bounds__(512, 1)
void gemm_bt(const __bf16* __restrict__ A, const __bf16* __restrict__ W,
             const float* __restrict__ bias, const AddT* __restrict__ add,
             OutT* __restrict__ C, int N, int K, int nN)
{
    constexpr int BK  = 32;
    constexpr int ASZ = 256 * BK;           // 8192 elems = 16 cells
    constexpr int BSZ = 192 * BK;           // 6144 elems = 12 cells
    __shared__ __bf16 L[4][ASZ + BSZ];      // ring-4: 112 KB
    const int tid = threadIdx.x, lane = tid & 63, wid = tid >> 6;
    const int lr = lane & 15, kh = lane >> 4;
    const int wm = wid >> 2, wn = wid & 3;       // wave grid 2(M) x 4(N)

    // XCD-chunked bijective swizzle (m204), N-fastest decode
    const int nwg = gridDim.x, bid = blockIdx.x;
    const int q = nwg >> 3, r = nwg & 7;
    const int xcd = bid & 7, jc = bid >> 3;
    const int wgid = (xcd < r ? xcd * (q + 1) : r * (q + 1) + (xcd - r) * q) + jc;
    const int mblk = wgid / nN, nblk = wgid - mblk * nN;
    const int m0 = mblk * 256, n0 = nblk * 192;

    const __bf16* pA = A + (size_t)(m0 + wid * 32 + lr) * K + kh * 8;
    const __bf16* pW = W + (size_t)(n0 + (wid < 6 ? wid : 0) * 32 + lr) * K + kh * 8;

    auto stageA = [&](int s, int kt) {
#pragma unroll
        for (int i = 0; i < 2; ++i)
            gld16(pA + (size_t)(i * 16) * K + kt * BK, &L[s][(wid * 2 + i) * 512]);
    };
    auto stageB = [&](int s, int kt) {
        if (wid < 6) {
#pragma unroll
            for (int i = 0; i < 2; ++i)
                gld16(pW + (size_t)(i * 16) * K + kt * BK,
                      &L[s][ASZ + (wid * 2 + i) * 512]);
        }
    };

    const int lo = lane * 8;   // lane-linear offset within a 512-elem cell

    f32x4 acc[8][3] = {};
    const int NT = K / BK;

    stageA(0, 0); stageB(0, 0);
    stageA(1, 1); stageB(1, 1);

    for (int t = 0; t < NT; ++t) {
        if (t + 1 < NT) {
            if (wid < 6) asm volatile("s_waitcnt vmcnt(4)" ::: "memory");
            else         asm volatile("s_waitcnt vmcnt(2)" ::: "memory");
        } else {
            asm volatile("s_waitcnt vmcnt(0)" ::: "memory");
        }
        __builtin_amdgcn_s_barrier();

        const __bf16* Ls = L[t & 3];
        v8bf bfr[3], afr[4];

        // ---- phase 0: reads (B all + A half 0), stage A(t+2), MFMA ----
#pragma unroll
        for (int nf = 0; nf < 3; ++nf)
            bfr[nf] = *(const v8bf*)&Ls[ASZ + (wn * 3 + nf) * 512 + lo];
#pragma unroll
        for (int mf = 0; mf < 4; ++mf)
            afr[mf] = *(const v8bf*)&Ls[(wm * 8 + mf) * 512 + lo];

        if (t + 2 < NT) stageA((t + 2) & 3, t + 2);

        __builtin_amdgcn_s_setprio(1);
#pragma unroll
        for (int mf = 0; mf < 4; ++mf)
#pragma unroll
            for (int nf = 0; nf < 3; ++nf)
                acc[mf][nf] = __builtin_amdgcn_mfma_f32_16x16x32_bf16(
                    afr[mf], bfr[nf], acc[mf][nf], 0, 0, 0);
        __builtin_amdgcn_s_setprio(0);
        __builtin_amdgcn_s_barrier();

        // ---- phase 1: reads (A half 1), stage B(t+2), MFMA ----
#pragma unroll
        for (int mf = 0; mf < 4; ++mf)
            afr[mf] = *(const v8bf*)&Ls[(wm * 8 + 4 + mf) * 512 + lo];

        if (t + 2 < NT) stageB((t + 2) & 3, t + 2);

        __builtin_amdgcn_s_setprio(1);
#pragma unroll
        for (int mf = 0; mf < 4; ++mf)
#pragma unroll
            for (int nf = 0; nf < 3; ++nf)
                acc[4 + mf][nf] = __builtin_amdgcn_mfma_f32_16x16x32_bf16(
                    afr[mf], bfr[nf], acc[4 + mf][nf], 0, 0, 0);
        __builtin_amdgcn_s_setprio(0);
    }

    // ---- epilogue (16x16 C/D layout: col=lane&15, row=(lane>>4)*4+reg) ----
#pragma unroll
    for (int mf = 0; mf < 8; ++mf)
#pragma unroll
        for (int nf = 0; nf < 3; ++nf)
#pragma unroll
            for (int rr = 0; rr < 4; ++rr) {
                int row = m0 + wm * 128 + mf * 16 + kh * 4 + rr;
                int col = n0 + wn * 48 + nf * 16 + lr;
                float vv = acc[mf][nf][rr] + bias[col];
                if (EPI == 1) vv += (float)add[(size_t)row * N + col];
                if (EPI == 2) vv = fast_gelu(vv);
                C[(size_t)row * N + col] = (OutT)vv;
            }
}

// ---- GEMM variant for fc1: r9 schedule, 256 thr / 4 waves, RING-4 = 80 KB
// (exactly 160/2 -> still 2 INDEPENDENT blocks/CU) with STAGE-AHEAD-3:
// counted vmcnt(10) means tile t's 5 loads were issued 3 tiles (~3000 cy)
// earlier — deeper cover than ring-3/ahead-2 while keeping the cross-block
// overlap (m114) that won r21. Race-free by the same induction: stage(t+3)
// targets slot (t-1)&3 whose reads drained before each wave's tile-(t-1)
// MFMAs, which precede barrier(t); the stage issues after barrier(t).
// Tile 128x192, wave tile 128x48. C = gelu(A@W^T + bias), bf16.
__global__ __launch_bounds__(256, 2)
void gemm_bt2(const __bf16* __restrict__ A, const __bf16* __restrict__ W,
              const float* __restrict__ bias, __bf16* __restrict__ C,
              int N, int K, int nN)
{
    constexpr int BK  = 32;
    constexpr int ASZ = 128 * BK;           // 4096 elems = 8 cells
    constexpr int BSZ = 192 * BK;           // 6144 elems = 12 cells
    __shared__ __bf16 L[4][ASZ + BSZ];      // ring-4: 80 KB -> 2 blocks/CU
    const int tid = threadIdx.x, lane = tid & 63, wid = tid >> 6;   // 0..3
    const int lr = lane & 15, kh = lane >> 4;
    const int wn = wid;                     // 4 waves across N

    // XCD-chunked bijective swizzle (m204), N-fastest decode
    const int nwg = gridDim.x, bid = blockIdx.x;
    const int q = nwg >> 3, r = nwg & 7;
    const int xcd = bid & 7, jc = bid >> 3;
    const int wgid = (xcd < r ? xcd * (q + 1) : r * (q + 1) + (xcd - r) * q) + jc;
    const int mblk = wgid / nN, nblk = wgid - mblk * nN;
    const int m0 = mblk * 128, n0 = nblk * 192;

    // staging: wave wid -> A cells {2wid,2wid+1} (rows wid*32..+32),
    //                       B cells {3wid..3wid+2} (rows wid*48..+48)
    const __bf16* pA = A + (size_t)(m0 + wid * 32 + lr) * K + kh * 8;
    const __bf16* pW = W + (size_t)(n0 + wid * 48 + lr) * K + kh * 8;

    auto stageA = [&](int s, int kt) {
#pragma unroll
        for (int i = 0; i < 2; ++i)
            gld16(pA + (size_t)(i * 16) * K + kt * BK, &L[s][(wid * 2 + i) * 512]);
    };
    auto stageB = [&](int s, int kt) {
#pragma unroll
        for (int i = 0; i < 3; ++i)
            gld16(pW + (size_t)(i * 16) * K + kt * BK,
                  &L[s][ASZ + (wid * 3 + i) * 512]);
    };

    const int lo = lane * 8;   // lane-linear offset within a 512-elem cell

    f32x4 acc[8][3] = {};
    const int NT = K / BK;     // 18

    stageA(0, 0); stageB(0, 0);
    stageA(1, 1); stageB(1, 1);
    stageA(2, 2); stageB(2, 2);

    for (int t = 0; t < NT; ++t) {
        // certify tile t: own-wave 5 loads/tile; tiles t+1,t+2's 10 stay in flight
        const int rem = NT - 1 - t;
        if (rem >= 2)      asm volatile("s_waitcnt vmcnt(10)" ::: "memory");
        else if (rem == 1) asm volatile("s_waitcnt vmcnt(5)"  ::: "memory");
        else               asm volatile("s_waitcnt vmcnt(0)"  ::: "memory");
        __builtin_amdgcn_s_barrier();

        const __bf16* Ls = L[t & 3];
        v8bf bfr[3], afr[4];

        // ---- phase 0: reads (B all + A cells 0-3), stage A(t+3), 12 MFMA ----
#pragma unroll
        for (int nf = 0; nf < 3; ++nf)
            bfr[nf] = *(const v8bf*)&Ls[ASZ + (wn * 3 + nf) * 512 + lo];
#pragma unroll
        for (int mf = 0; mf < 4; ++mf)
            afr[mf] = *(const v8bf*)&Ls[mf * 512 + lo];

        if (t + 3 < NT) stageA((t + 3) & 3, t + 3);

        __builtin_amdgcn_s_setprio(1);
#pragma unroll
        for (int mf = 0; mf < 4; ++mf)
#pragma unroll
            for (int nf = 0; nf < 3; ++nf)
                acc[mf][nf] = __builtin_amdgcn_mfma_f32_16x16x32_bf16(
                    afr[mf], bfr[nf], acc[mf][nf], 0, 0, 0);
        __builtin_amdgcn_s_setprio(0);
        __builtin_amdgcn_s_barrier();

        // ---- phase 1: reads (A cells 4-7), stage B(t+3), 12 MFMA ----
#pragma unroll
        for (int mf = 0; mf < 4; ++mf)
            afr[mf] = *(const v8bf*)&Ls[(4 + mf) * 512 + lo];

        if (t + 3 < NT) stageB((t + 3) & 3, t + 3);

        __builtin_amdgcn_s_setprio(1);
#pragma unroll
        for (int mf = 0; mf < 4; ++mf)
#pragma unroll
            for (int nf = 0; nf < 3; ++nf)
                acc[4 + mf][nf] = __builtin_amdgcn_mfma_f32_16x16x32_bf16(
                    afr[mf], bfr[nf], acc[4 + mf][nf], 0, 0, 0);
        __builtin_amdgcn_s_setprio(0);
    }

    // ---- epilogue: bias + exact GELU, bf16 out ----
#pragma unroll
    for (int mf = 0; mf < 8; ++mf)
#pragma unroll
        for (int nf = 0; nf < 3; ++nf)
#pragma unroll
            for (int rr = 0; rr < 4; ++rr) {
                int row = m0 + mf * 16 + kh * 4 + rr;
                int col = n0 + wn * 48 + nf * 16 + lr;
                float vv = fast_gelu(acc[mf][nf][rr] + bias[col]);
                C[(size_t)row * N + col] = (__bf16)vv;
            }
}

// -------- Windowed attention: one wave per (head, window), vectorized --------
__global__ __launch_bounds__(64)
void attn_kernel(const __bf16* __restrict__ qkv, const float* __restrict__ biases,
                 const int* __restrict__ bidx, __bf16* __restrict__ out)
{
    const int head = blockIdx.x;
    const int win  = blockIdx.y;
    const int tid  = threadIdx.x;
    const int b  = win >> 4;
    const int wy = (win >> 2) & 3;
    const int wx = win & 3;
    __shared__ float kk[49][32];
    __shared__ float vv[49][32];
    const size_t hb = (size_t)head * 96;

    for (int e = tid; e < 196; e += 64) {
        const int n = e >> 2, j = e & 3;
        const int iy = n / 7, ix = n - iy * 7;
        const size_t t = (size_t)b * 784 + (size_t)(wy * 7 + iy) * 28 + wx * 7 + ix;
        const __bf16* p = qkv + t * QKVD + hb;
        v8bf k8 = *(const v8bf*)&p[32 + j * 8];
        v8bf v8 = *(const v8bf*)&p[64 + j * 8];
        f32x4 k0, k1, v0, v1;
#pragma unroll
        for (int r = 0; r < 4; ++r) {
            k0[r] = (float)k8[r]; k1[r] = (float)k8[4 + r];
            v0[r] = (float)v8[r]; v1[r] = (float)v8[4 + r];
        }
        *(f32x4*)&kk[n][j * 8]     = k0;
        *(f32x4*)&kk[n][j * 8 + 4] = k1;
        *(f32x4*)&vv[n][j * 8]     = v0;
        *(f32x4*)&vv[n][j * 8 + 4] = v1;
    }
    f32x4 qv[8];
    size_t tmine = 0;
    if (tid < 49) {
        const int iy = tid / 7, ix = tid - iy * 7;
        tmine = (size_t)b * 784 + (size_t)(wy * 7 + iy) * 28 + wx * 7 + ix;
        const __bf16* p = qkv + tmine * QKVD + hb;
#pragma unroll
        for (int jj = 0; jj < 4; ++jj) {
            v8bf q8 = *(const v8bf*)&p[jj * 8];
#pragma unroll
            for (int r = 0; r < 4; ++r) {
                qv[2 * jj][r]     = (float)q8[r];
                qv[2 * jj + 1][r] = (float)q8[4 + r];
            }
        }
    }
    __syncthreads();
    if (tid >= 49) return;

    const float scale = 0.17677669529663687f;
    float s[49];
    float mx = -1e30f;
    const int*   brow = bidx + tid * 49;
    const float* bh   = biases + head * 49;
#pragma unroll
    for (int m = 0; m < 49; ++m) {
        const f32x4* krow = (const f32x4*)&kk[m][0];
        f32x4 d4 = {0.f, 0.f, 0.f, 0.f};
#pragma unroll
        for (int j = 0; j < 8; ++j) d4 += qv[j] * krow[j];
        float val = (d4[0] + d4[1] + d4[2] + d4[3]) * scale + bh[brow[m]];
        s[m] = val;
        mx = fmaxf(mx, val);
    }
    float sum = 0.f;
#pragma unroll
    for (int m = 0; m < 49; ++m) { float e = __expf(s[m] - mx); s[m] = e; sum += e; }
    const float rs = 1.0f / sum;

    f32x4 av[8] = {};
#pragma unroll
    for (int m = 0; m < 49; ++m) {
        const float sm = s[m];
        const f32x4* vrow = (const f32x4*)&vv[m][0];
#pragma unroll
        for (int j = 0; j < 8; ++j) av[j] += sm * vrow[j];
    }

    __bf16* op = out + tmine * CDIM + (size_t)head * 32;
#pragma unroll
    for (int jj = 0; jj < 4; ++jj) {
        v8bf o;
#pragma unroll
        for (int r = 0; r < 4; ++r) {
            o[r]     = (__bf16)(av[2 * jj][r] * rs);
            o[4 + r] = (__bf16)(av[2 * jj + 1][r] * rs);
        }
        *(v8bf*)&op[jj * 8] = o;
    }
}

// ------- Fused depthwise 3x3 conv + folded BN + LayerNorm: one wave/token -------
// Reads x2 (3x3 neighborhood); writes x3 and lnm. lnm must not alias x2.
__global__ __launch_bounds__(256)
void conv_bn_ln(const __bf16* __restrict__ xin, const __bf16* __restrict__ wt,
                const float* __restrict__ bias2, const float* __restrict__ g,
                const float* __restrict__ b,
                __bf16* __restrict__ x3, __bf16* __restrict__ lnm)
{
    const int lane = threadIdx.x & 63;
    const int wid  = threadIdx.x >> 6;
    const size_t p = (size_t)blockIdx.x * 4 + wid;          // token
    const int bimg = (int)(p / 784);
    const int pix  = (int)(p - (size_t)bimg * 784);
    const int y = pix / 28, xx = pix - y * 28;
    const size_t rowbase = (size_t)bimg * 784;

    float v[16];
    float sum = 0.f, sq = 0.f;

    {
        const int c0 = lane * 8;
        float a[8];
        f32x4 b0 = *(const f32x4*)&bias2[c0];
        f32x4 b1 = *(const f32x4*)&bias2[c0 + 4];
#pragma unroll
        for (int j = 0; j < 4; ++j) { a[j] = b0[j]; a[4 + j] = b1[j]; }
#pragma unroll
        for (int dy = 0; dy < 3; ++dy) {
            int ny = y + dy - 1;
            if (ny < 0 || ny >= 28) continue;
#pragma unroll
            for (int dx = 0; dx < 3; ++dx) {
                int nx = xx + dx - 1;
                if (nx < 0 || nx >= 28) continue;
                v8bf xv = *(const v8bf*)&xin[(rowbase + ny * 28 + nx) * CDIM + c0];
                v8bf wv = *(const v8bf*)&wt[(dy * 3 + dx) * CDIM + c0];
#pragma unroll
                for (int j = 0; j < 8; ++j) a[j] += (float)xv[j] * (float)wv[j];
            }
        }
#pragma unroll
        for (int j = 0; j < 8; ++j) { v[j] = a[j]; sum += a[j]; sq += a[j] * a[j]; }
    }
    if (lane < 8) {
        const int c0 = 512 + lane * 8;
        float a[8];
        f32x4 b0 = *(const f32x4*)&bias2[c0];
        f32x4 b1 = *(const f32x4*)&bias2[c0 + 4];
#pragma unroll
        for (int j = 0; j < 4; ++j) { a[j] = b0[j]; a[4 + j] = b1[j]; }
#pragma unroll
        for (int dy = 0; dy < 3; ++dy) {
            int ny = y + dy - 1;
            if (ny < 0 || ny >= 28) continue;
#pragma unroll
            for (int dx = 0; dx < 3; ++dx) {
                int nx = xx + dx - 1;
                if (nx < 0 || nx >= 28) continue;
                v8bf xv = *(const v8bf*)&xin[(rowbase + ny * 28 + nx) * CDIM + c0];
                v8bf wv = *(const v8bf*)&wt[(dy * 3 + dx) * CDIM + c0];
#pragma unroll
                for (int j = 0; j < 8; ++j) a[j] += (float)xv[j] * (float)wv[j];
            }
        }
#pragma unroll
        for (int j = 0; j < 8; ++j) { v[8 + j] = a[j]; sum += a[j]; sq += a[j] * a[j]; }
    }

#pragma unroll
    for (int o = 32; o >= 1; o >>= 1) {
        sum += __shfl_xor(sum, o, 64);
        sq  += __shfl_xor(sq,  o, 64);
    }
    const float mean = sum * (1.0f / CDIM);
    const float rstd = rsqrtf(sq * (1.0f / CDIM) - mean * mean + 1e-5f);

    {
        const int c0 = lane * 8;
        v8bf o3, ol;
#pragma unroll
        for (int j = 0; j < 8; ++j) {
            o3[j] = (__bf16)v[j];
            ol[j] = (__bf16)((v[j] - mean) * rstd * g[c0 + j] + b[c0 + j]);
        }
        *(v8bf*)&x3[p * CDIM + c0]  = o3;
        *(v8bf*)&lnm[p * CDIM + c0] = ol;
    }
    if (lane < 8) {
        const int c0 = 512 + lane * 8;
        v8bf o3, ol;
#pragma unroll
        for (int j = 0; j < 8; ++j) {
            o3[j] = (__bf16)v[8 + j];
            ol[j] = (__bf16)((v[8 + j] - mean) * rstd * g[c0 + j] + b[c0 + j]);
        }
        *(v8bf*)&x3[p * CDIM + c0]  = o3;
        *(v8bf*)&lnm[p * CDIM + c0] = ol;
    }
}

extern "C" void kernel_launch(void* const* d_in, const int* in_sizes, int n_in,
                              void* d_out, int out_size, void* d_ws, size_t ws_size,
                              hipStream_t stream)
{
    (void)in_sizes; (void)n_in; (void)out_size; (void)ws_size;
    const float* x          = (const float*)d_in[0];
    const float* gamma_a    = (const float*)d_in[1];
    const float* beta_a     = (const float*)d_in[2];
    const float* qkv_w      = (const float*)d_in[3];
    const float* qkv_b      = (const float*)d_in[4];
    const float* proj_w     = (const float*)d_in[5];
    const float* proj_b     = (const float*)d_in[6];
    const float* attn_bias  = (const float*)d_in[7];
    const float* conv_w     = (const float*)d_in[8];
    const float* bn_g       = (const float*)d_in[9];
    const float* bn_b       = (const float*)d_in[10];
    const float* bn_m       = (const float*)d_in[11];
    const float* bn_v       = (const float*)d_in[12];
    const float* gamma_m    = (const float*)d_in[13];
    const float* beta_m     = (const float*)d_in[14];
    const float* fc1_w      = (const float*)d_in[15];
    const float* fc1_b      = (const float*)d_in[16];
    const float* fc2_w      = (const float*)d_in[17];
    const float* fc2_b      = (const float*)d_in[18];
    const int*   bidx       = (const int*)d_in[19];

    const size_t T = TOKENS;
    // ---- workspace layout (bf16 elems) — alias-audited per stage ----
    // [0,T*576)         hbuf (LN_a out) -> aout (attn out) -> lnm (conv_bn_ln out)
    // [T*576,T*2304)    qkvbuf -> (joins f1)
    // [T*2304,T*2880)   x2 (proj out) -> (tail of f1)
    // f1 = [T*576, T*2880)  (qkvbuf+x2, both dead at fc1; disjoint from lnm)
    // [T*2880,T*3456)   x3 (conv out, residual for fc2); weights after.
    __bf16* ws     = (__bf16*)d_ws;
    __bf16* hbuf   = ws;
    __bf16* qkvbuf = ws + T * 576;
    __bf16* aout   = ws;                 // reuse hbuf
    __bf16* x2     = ws + T * 2304;
    __bf16* x3     = ws + T * 2880;
    __bf16* lnm    = ws;                 // reuse hbuf/aout (dead after proj)
    __bf16* f1     = ws + T * 576;       // qkvbuf + x2 regions (dead at fc1)
    __bf16* wq     = x3 + T * 576;                   // qkv_w bf16  [1728*576]
    __bf16* wp     = wq + (size_t)QKVD * CDIM;       // proj_w bf16 [576*576]
    __bf16* w1     = wp + (size_t)CDIM * CDIM;       // fc1_w bf16  [2304*576]
    __bf16* w2     = w1 + (size_t)2304 * CDIM;       // fc2_w bf16  [576*2304]
    __bf16* wt     = w2 + (size_t)CDIM * 2304;       // conv wt [9][576]
    float*  bias2  = (float*)(wt + 9 * CDIM);        // conv bias [576]
    float*  outp   = (float*)d_out;

    // all 4 weight casts in one launch (dests contiguous starting at wq)
    cast4_kernel<<<dim3(3888), 256, 0, stream>>>(qkv_w, proj_w, fc1_w, fc2_w, wq);
    conv_prep<<<dim3(9), 64, 0, stream>>>(conv_w, bn_g, bn_b, bn_m, bn_v, wt, bias2);

    ln_kernel<<<dim3(T / 4), 256, 0, stream>>>(x, gamma_a, beta_a, hbuf);
    gemm_bt<0, __bf16, float><<<dim3(196 * 9), 512, 0, stream>>>(
        hbuf, wq, qkv_b, nullptr, qkvbuf, QKVD, CDIM, 9);
    attn_kernel<<<dim3(NHEAD, 1024), 64, 0, stream>>>(qkvbuf, attn_bias, bidx, aout);
    gemm_bt<1, __bf16, float><<<dim3(196 * 3), 512, 0, stream>>>(
        aout, wp, proj_b, x, x2, CDIM, CDIM, 3);
    conv_bn_ln<<<dim3(12544), 256, 0, stream>>>(x2, wt, bias2, gamma_m, beta_m,
                                                x3, lnm);
    gemm_bt2<<<dim3(392 * 12), 256, 0, stream>>>(
        lnm, w1, fc1_b, f1, 2304, CDIM, 12);
    gemm_bt<1, float, __bf16><<<dim3(196 * 3), 512, 0, stream>>>(
        f1, w2, fc2_b, x3, outp, CDIM, 2304, 3);
}

// Round 26
// 979.707 us; speedup vs baseline: 1.0031x; 1.0031x over previous
//
#include <hip/hip_runtime.h>
#include <hip/hip_bf16.h>

typedef __bf16 v8bf  __attribute__((ext_vector_type(8)));
typedef __bf16 v4bf  __attribute__((ext_vector_type(4)));
typedef float  f32x4 __attribute__((ext_vector_type(4)));
typedef float  f32x8 __attribute__((ext_vector_type(8)));

#define TOKENS 50176
#define CDIM   576
#define NHEAD  18
#define QKVD   1728

// async global->LDS, 16B per lane; LDS dest = wave-uniform base + lane*16
__device__ __forceinline__ void gld16(const __bf16* g, __bf16* l)
{
    __builtin_amdgcn_global_load_lds(
        (const __attribute__((address_space(1))) void*)g,
        (__attribute__((address_space(3))) void*)l,
        16, 0, 0);
}

// exact-GELU via Abramowitz-Stegun 7.1.26 erf (|err| <= 1.5e-7, below bf16 eps)
__device__ __forceinline__ float fast_gelu(float x)
{
    const float z  = x * 0.70710678118654752f;
    const float az = fabsf(z);
    const float t  = __frcp_rn(1.0f + 0.3275911f * az);
    float p = 1.061405429f;
    p = p * t - 1.453152027f;
    p = p * t + 1.421413741f;
    p = p * t - 0.284496736f;
    p = p * t + 0.254829592f;
    const float e   = __expf(-z * z);
    float erfv = 1.0f - p * t * e;
    erfv = copysignf(erfv, z);
    return 0.5f * x * (1.0f + erfv);
}

// ---- fused f32->bf16 cast of all 4 GEMM weights (dests contiguous in ws) ----
__global__ __launch_bounds__(256)
void cast4_kernel(const float* __restrict__ s0, const float* __restrict__ s1,
                  const float* __restrict__ s2, const float* __restrict__ s3,
                  __bf16* __restrict__ dst)
{
    const size_t i = ((size_t)blockIdx.x * 256 + threadIdx.x) * 4;
    constexpr size_t n0 = (size_t)QKVD * CDIM;            // 995328
    constexpr size_t n1 = n0 + (size_t)CDIM * CDIM;       // +331776
    constexpr size_t n2 = n1 + (size_t)2304 * CDIM;       // +1327104
    const float* s; size_t off;
    if (i < n0)      { s = s0; off = i; }
    else if (i < n1) { s = s1; off = i - n0; }
    else if (i < n2) { s = s2; off = i - n1; }
    else             { s = s3; off = i - n2; }
    f32x4 v = *(const f32x4*)&s[off];
    v4bf o;
#pragma unroll
    for (int j = 0; j < 4; ++j) o[j] = (__bf16)v[j];
    *(v4bf*)&dst[i] = o;
}

// ------- conv weight prep: fold BN scale into weights, make [9][576] bf16 -------
__global__ __launch_bounds__(64)
void conv_prep(const float* __restrict__ w, const float* __restrict__ bg,
               const float* __restrict__ bb, const float* __restrict__ bm,
               const float* __restrict__ bv, __bf16* __restrict__ wt,
               float* __restrict__ bias2)
{
    const int c = blockIdx.x * 64 + threadIdx.x;   // 576
    const float inv = rsqrtf(bv[c] + 1e-5f) * bg[c];
#pragma unroll
    for (int t = 0; t < 9; ++t) wt[t * CDIM + c] = (__bf16)(w[c * 9 + t] * inv);
    bias2[c] = bb[c] - bm[c] * inv;
}

// ---------------- LayerNorm (LN_a): one wave per token, f32 in, bf16 out ----
__global__ __launch_bounds__(256)
void ln_kernel(const float* __restrict__ x, const float* __restrict__ g,
               const float* __restrict__ b, __bf16* __restrict__ out)
{
    const int lane = threadIdx.x & 63;
    const int wid  = threadIdx.x >> 6;
    const size_t t = (size_t)blockIdx.x * 4 + wid;
    const float* row = x + t * CDIM;

    float v[16];
    float sum = 0.f, sq = 0.f;
    {
        f32x8 d0 = *(const f32x8*)&row[(size_t)lane * 8];
#pragma unroll
        for (int j = 0; j < 8; ++j) { float f = d0[j]; v[j] = f; sum += f; sq += f * f; }
    }
    if (lane < 8) {
        f32x8 d1 = *(const f32x8*)&row[(size_t)(lane + 64) * 8];
#pragma unroll
        for (int j = 0; j < 8; ++j) { float f = d1[j]; v[8 + j] = f; sum += f; sq += f * f; }
    }
#pragma unroll
    for (int o = 32; o >= 1; o >>= 1) {
        sum += __shfl_xor(sum, o, 64);
        sq  += __shfl_xor(sq,  o, 64);
    }
    const float mean = sum * (1.0f / CDIM);
    const float rstd = rsqrtf(sq * (1.0f / CDIM) - mean * mean + 1e-5f);

    {
        int c0 = lane * 8;
        v8bf o0;
#pragma unroll
        for (int j = 0; j < 8; ++j)
            o0[j] = (__bf16)((v[j] - mean) * rstd * g[c0 + j] + b[c0 + j]);
        *(v8bf*)&out[t * CDIM + c0] = o0;
    }
    if (lane < 8) {
        int c0 = (lane + 64) * 8;
        v8bf o1;
#pragma unroll
        for (int j = 0; j < 8; ++j)
            o1[j] = (__bf16)((v[8 + j] - mean) * rstd * g[c0 + j] + b[c0 + j]);
        *(v8bf*)&out[t * CDIM + c0] = o1;
    }
}

// ------- GEMM (big-tile; best for qkv/proj/fc2): r9 schedule, 512 thr ------
// Tile 256x192, BK=32, 8 waves (2M x 4N), ring-4 LDS 112 KB, stage-ahead-2,
// counted per-wave vmcnt. Subtiled 1KB LDS cells (16 rows x 32 k,
// lane-linear): conflict-free b128, linear gld16 dest.
// EPI: 0 = none, 1 = += add[M][N], 2 = exact GELU
template<int EPI, typename OutT, typename AddT>
__global__ __launch_bounds__(512, 1)
void gemm_bt(const __bf16* __restrict__ A, const __bf16* __restrict__ W,
             const float* __restrict__ bias, const AddT* __restrict__ add,
             OutT* __restrict__ C, int N, int K, int nN)
{
    constexpr int BK  = 32;
    constexpr int ASZ = 256 * BK;           // 8192 elems = 16 cells
    constexpr int BSZ = 192 * BK;           // 6144 elems = 12 cells
    __shared__ __bf16 L[4][ASZ + BSZ];      // ring-4: 112 KB
    const int tid = threadIdx.x, lane = tid & 63, wid = tid >> 6;
    const int lr = lane & 15, kh = lane >> 4;
    const int wm = wid >> 2, wn = wid & 3;       // wave grid 2(M) x 4(N)

    // XCD-chunked bijective swizzle (m204), N-fastest decode
    const int nwg = gridDim.x, bid = blockIdx.x;
    const int q = nwg >> 3, r = nwg & 7;
    const int xcd = bid & 7, jc = bid >> 3;
    const int wgid = (xcd < r ? xcd * (q + 1) : r * (q + 1) + (xcd - r) * q) + jc;
    const int mblk = wgid / nN, nblk = wgid - mblk * nN;
    const int m0 = mblk * 256, n0 = nblk * 192;

    const __bf16* pA = A + (size_t)(m0 + wid * 32 + lr) * K + kh * 8;
    const __bf16* pW = W + (size_t)(n0 + (wid < 6 ? wid : 0) * 32 + lr) * K + kh * 8;

    auto stageA = [&](int s, int kt) {
#pragma unroll
        for (int i = 0; i < 2; ++i)
            gld16(pA + (size_t)(i * 16) * K + kt * BK, &L[s][(wid * 2 + i) * 512]);
    };
    auto stageB = [&](int s, int kt) {
        if (wid < 6) {
#pragma unroll
            for (int i = 0; i < 2; ++i)
                gld16(pW + (size_t)(i * 16) * K + kt * BK,
                      &L[s][ASZ + (wid * 2 + i) * 512]);
        }
    };

    const int lo = lane * 8;   // lane-linear offset within a 512-elem cell

    f32x4 acc[8][3] = {};
    const int NT = K / BK;

    stageA(0, 0); stageB(0, 0);
    stageA(1, 1); stageB(1, 1);

    for (int t = 0; t < NT; ++t) {
        if (t + 1 < NT) {
            if (wid < 6) asm volatile("s_waitcnt vmcnt(4)" ::: "memory");
            else         asm volatile("s_waitcnt vmcnt(2)" ::: "memory");
        } else {
            asm volatile("s_waitcnt vmcnt(0)" ::: "memory");
        }
        __builtin_amdgcn_s_barrier();

        const __bf16* Ls = L[t & 3];
        v8bf bfr[3], afr[4];

        // ---- phase 0: reads (B all + A half 0), stage A(t+2), MFMA ----
#pragma unroll
        for (int nf = 0; nf < 3; ++nf)
            bfr[nf] = *(const v8bf*)&Ls[ASZ + (wn * 3 + nf) * 512 + lo];
#pragma unroll
        for (int mf = 0; mf < 4; ++mf)
            afr[mf] = *(const v8bf*)&Ls[(wm * 8 + mf) * 512 + lo];

        if (t + 2 < NT) stageA((t + 2) & 3, t + 2);

        __builtin_amdgcn_s_setprio(1);
#pragma unroll
        for (int mf = 0; mf < 4; ++mf)
#pragma unroll
            for (int nf = 0; nf < 3; ++nf)
                acc[mf][nf] = __builtin_amdgcn_mfma_f32_16x16x32_bf16(
                    afr[mf], bfr[nf], acc[mf][nf], 0, 0, 0);
        __builtin_amdgcn_s_setprio(0);
        __builtin_amdgcn_s_barrier();

        // ---- phase 1: reads (A half 1), stage B(t+2), MFMA ----
#pragma unroll
        for (int mf = 0; mf < 4; ++mf)
            afr[mf] = *(const v8bf*)&Ls[(wm * 8 + 4 + mf) * 512 + lo];

        if (t + 2 < NT) stageB((t + 2) & 3, t + 2);

        __builtin_amdgcn_s_setprio(1);
#pragma unroll
        for (int mf = 0; mf < 4; ++mf)
#pragma unroll
            for (int nf = 0; nf < 3; ++nf)
                acc[4 + mf][nf] = __builtin_amdgcn_mfma_f32_16x16x32_bf16(
                    afr[mf], bfr[nf], acc[4 + mf][nf], 0, 0, 0);
        __builtin_amdgcn_s_setprio(0);
    }

    // ---- epilogue (16x16 C/D layout: col=lane&15, row=(lane>>4)*4+reg) ----
#pragma unroll
    for (int mf = 0; mf < 8; ++mf)
#pragma unroll
        for (int nf = 0; nf < 3; ++nf)
#pragma unroll
            for (int rr = 0; rr < 4; ++rr) {
                int row = m0 + wm * 128 + mf * 16 + kh * 4 + rr;
                int col = n0 + wn * 48 + nf * 16 + lr;
                float vv = acc[mf][nf][rr] + bias[col];
                if (EPI == 1) vv += (float)add[(size_t)row * N + col];
                if (EPI == 2) vv = fast_gelu(vv);
                C[(size_t)row * N + col] = (OutT)vv;
            }
}

// ---- GEMM variant for fc1 (r21-proven win): r9 schedule, 256 thr / 4 waves,
// ring-3 = 60 KB -> 2 INDEPENDENT blocks/CU (cross-block overlap covers the
// counted-vmcnt/barrier stalls — m114 mechanism, +5% on fc1).
// Tile 128x192, wave tile 128x48 (wave wid owns N-slice wid*48). Per wave
// per tile: stage 2 A-cells (ph0) + 3 B-cells (ph1) -> counted vmcnt(5).
// Output: C = gelu(A@W^T + bias), bf16.
__global__ __launch_bounds__(256, 2)
void gemm_bt2(const __bf16* __restrict__ A, const __bf16* __restrict__ W,
              const float* __restrict__ bias, __bf16* __restrict__ C,
              int N, int K, int nN)
{
    constexpr int BK  = 32;
    constexpr int ASZ = 128 * BK;           // 4096 elems = 8 cells
    constexpr int BSZ = 192 * BK;           // 6144 elems = 12 cells
    __shared__ __bf16 L[3][ASZ + BSZ];      // ring-3: 60 KB -> 2 blocks/CU
    const int tid = threadIdx.x, lane = tid & 63, wid = tid >> 6;   // 0..3
    const int lr = lane & 15, kh = lane >> 4;
    const int wn = wid;                     // 4 waves across N

    // XCD-chunked bijective swizzle (m204), N-fastest decode
    const int nwg = gridDim.x, bid = blockIdx.x;
    const int q = nwg >> 3, r = nwg & 7;
    const int xcd = bid & 7, jc = bid >> 3;
    const int wgid = (xcd < r ? xcd * (q + 1) : r * (q + 1) + (xcd - r) * q) + jc;
    const int mblk = wgid / nN, nblk = wgid - mblk * nN;
    const int m0 = mblk * 128, n0 = nblk * 192;

    // staging: wave wid -> A cells {2wid,2wid+1} (rows wid*32..+32),
    //                       B cells {3wid..3wid+2} (rows wid*48..+48)
    const __bf16* pA = A + (size_t)(m0 + wid * 32 + lr) * K + kh * 8;
    const __bf16* pW = W + (size_t)(n0 + wid * 48 + lr) * K + kh * 8;

    auto stageA = [&](int s, int kt) {
#pragma unroll
        for (int i = 0; i < 2; ++i)
            gld16(pA + (size_t)(i * 16) * K + kt * BK, &L[s][(wid * 2 + i) * 512]);
    };
    auto stageB = [&](int s, int kt) {
#pragma unroll
        for (int i = 0; i < 3; ++i)
            gld16(pW + (size_t)(i * 16) * K + kt * BK,
                  &L[s][ASZ + (wid * 3 + i) * 512]);
    };

    const int lo = lane * 8;   // lane-linear offset within a 512-elem cell

    f32x4 acc[8][3] = {};
    const int NT = K / BK;     // 18

    stageA(0, 0); stageB(0, 0);
    stageA(1, 1); stageB(1, 1);

    for (int t = 0; t < NT; ++t) {
        // certify tile t (own-wave 5 loads); tile t+1's 5 stay in flight
        if (t + 1 < NT) asm volatile("s_waitcnt vmcnt(5)" ::: "memory");
        else            asm volatile("s_waitcnt vmcnt(0)" ::: "memory");
        __builtin_amdgcn_s_barrier();

        const __bf16* Ls = L[t % 3];
        v8bf bfr[3], afr[4];

        // ---- phase 0: reads (B all + A cells 0-3), stage A(t+2), 12 MFMA ----
#pragma unroll
        for (int nf = 0; nf < 3; ++nf)
            bfr[nf] = *(const v8bf*)&Ls[ASZ + (wn * 3 + nf) * 512 + lo];
#pragma unroll
        for (int mf = 0; mf < 4; ++mf)
            afr[mf] = *(const v8bf*)&Ls[mf * 512 + lo];

        if (t + 2 < NT) stageA((t + 2) % 3, t + 2);

        __builtin_amdgcn_s_setprio(1);
#pragma unroll
        for (int mf = 0; mf < 4; ++mf)
#pragma unroll
            for (int nf = 0; nf < 3; ++nf)
                acc[mf][nf] = __builtin_amdgcn_mfma_f32_16x16x32_bf16(
                    afr[mf], bfr[nf], acc[mf][nf], 0, 0, 0);
        __builtin_amdgcn_s_setprio(0);
        __builtin_amdgcn_s_barrier();

        // ---- phase 1: reads (A cells 4-7), stage B(t+2), 12 MFMA ----
#pragma unroll
        for (int mf = 0; mf < 4; ++mf)
            afr[mf] = *(const v8bf*)&Ls[(4 + mf) * 512 + lo];

        if (t + 2 < NT) stageB((t + 2) % 3, t + 2);

        __builtin_amdgcn_s_setprio(1);
#pragma unroll
        for (int mf = 0; mf < 4; ++mf)
#pragma unroll
            for (int nf = 0; nf < 3; ++nf)
                acc[4 + mf][nf] = __builtin_amdgcn_mfma_f32_16x16x32_bf16(
                    afr[mf], bfr[nf], acc[4 + mf][nf], 0, 0, 0);
        __builtin_amdgcn_s_setprio(0);
    }

    // ---- epilogue: bias + exact GELU, bf16 out ----
#pragma unroll
    for (int mf = 0; mf < 8; ++mf)
#pragma unroll
        for (int nf = 0; nf < 3; ++nf)
#pragma unroll
            for (int rr = 0; rr < 4; ++rr) {
                int row = m0 + mf * 16 + kh * 4 + rr;
                int col = n0 + wn * 48 + nf * 16 + lr;
                float vv = fast_gelu(acc[mf][nf][rr] + bias[col]);
                C[(size_t)row * N + col] = (__bf16)vv;
            }
}

// -------- Windowed attention: one wave per (head, window), vectorized --------
__global__ __launch_bounds__(64)
void attn_kernel(const __bf16* __restrict__ qkv, const float* __restrict__ biases,
                 const int* __restrict__ bidx, __bf16* __restrict__ out)
{
    const int head = blockIdx.x;
    const int win  = blockIdx.y;
    const int tid  = threadIdx.x;
    const int b  = win >> 4;
    const int wy = (win >> 2) & 3;
    const int wx = win & 3;
    __shared__ float kk[49][32];
    __shared__ float vv[49][32];
    const size_t hb = (size_t)head * 96;

    for (int e = tid; e < 196; e += 64) {
        const int n = e >> 2, j = e & 3;
        const int iy = n / 7, ix = n - iy * 7;
        const size_t t = (size_t)b * 784 + (size_t)(wy * 7 + iy) * 28 + wx * 7 + ix;
        const __bf16* p = qkv + t * QKVD + hb;
        v8bf k8 = *(const v8bf*)&p[32 + j * 8];
        v8bf v8 = *(const v8bf*)&p[64 + j * 8];
        f32x4 k0, k1, v0, v1;
#pragma unroll
        for (int r = 0; r < 4; ++r) {
            k0[r] = (float)k8[r]; k1[r] = (float)k8[4 + r];
            v0[r] = (float)v8[r]; v1[r] = (float)v8[4 + r];
        }
        *(f32x4*)&kk[n][j * 8]     = k0;
        *(f32x4*)&kk[n][j * 8 + 4] = k1;
        *(f32x4*)&vv[n][j * 8]     = v0;
        *(f32x4*)&vv[n][j * 8 + 4] = v1;
    }
    f32x4 qv[8];
    size_t tmine = 0;
    if (tid < 49) {
        const int iy = tid / 7, ix = tid - iy * 7;
        tmine = (size_t)b * 784 + (size_t)(wy * 7 + iy) * 28 + wx * 7 + ix;
        const __bf16* p = qkv + tmine * QKVD + hb;
#pragma unroll
        for (int jj = 0; jj < 4; ++jj) {
            v8bf q8 = *(const v8bf*)&p[jj * 8];
#pragma unroll
            for (int r = 0; r < 4; ++r) {
                qv[2 * jj][r]     = (float)q8[r];
                qv[2 * jj + 1][r] = (float)q8[4 + r];
            }
        }
    }
    __syncthreads();
    if (tid >= 49) return;

    const float scale = 0.17677669529663687f;
    float s[49];
    float mx = -1e30f;
    const int*   brow = bidx + tid * 49;
    const float* bh   = biases + head * 49;
#pragma unroll
    for (int m = 0; m < 49; ++m) {
        const f32x4* krow = (const f32x4*)&kk[m][0];
        f32x4 d4 = {0.f, 0.f, 0.f, 0.f};
#pragma unroll
        for (int j = 0; j < 8; ++j) d4 += qv[j] * krow[j];
        float val = (d4[0] + d4[1] + d4[2] + d4[3]) * scale + bh[brow[m]];
        s[m] = val;
        mx = fmaxf(mx, val);
    }
    float sum = 0.f;
#pragma unroll
    for (int m = 0; m < 49; ++m) { float e = __expf(s[m] - mx); s[m] = e; sum += e; }
    const float rs = 1.0f / sum;

    f32x4 av[8] = {};
#pragma unroll
    for (int m = 0; m < 49; ++m) {
        const float sm = s[m];
        const f32x4* vrow = (const f32x4*)&vv[m][0];
#pragma unroll
        for (int j = 0; j < 8; ++j) av[j] += sm * vrow[j];
    }

    __bf16* op = out + tmine * CDIM + (size_t)head * 32;
#pragma unroll
    for (int jj = 0; jj < 4; ++jj) {
        v8bf o;
#pragma unroll
        for (int r = 0; r < 4; ++r) {
            o[r]     = (__bf16)(av[2 * jj][r] * rs);
            o[4 + r] = (__bf16)(av[2 * jj + 1][r] * rs);
        }
        *(v8bf*)&op[jj * 8] = o;
    }
}

// ------- Fused depthwise 3x3 conv + folded BN + LayerNorm: one wave/token -------
// Reads x2 (3x3 neighborhood); writes x3 and lnm. lnm must not alias x2.
__global__ __launch_bounds__(256)
void conv_bn_ln(const __bf16* __restrict__ xin, const __bf16* __restrict__ wt,
                const float* __restrict__ bias2, const float* __restrict__ g,
                const float* __restrict__ b,
                __bf16* __restrict__ x3, __bf16* __restrict__ lnm)
{
    const int lane = threadIdx.x & 63;
    const int wid  = threadIdx.x >> 6;
    const size_t p = (size_t)blockIdx.x * 4 + wid;          // token
    const int bimg = (int)(p / 784);
    const int pix  = (int)(p - (size_t)bimg * 784);
    const int y = pix / 28, xx = pix - y * 28;
    const size_t rowbase = (size_t)bimg * 784;

    float v[16];
    float sum = 0.f, sq = 0.f;

    {
        const int c0 = lane * 8;
        float a[8];
        f32x4 b0 = *(const f32x4*)&bias2[c0];
        f32x4 b1 = *(const f32x4*)&bias2[c0 + 4];
#pragma unroll
        for (int j = 0; j < 4; ++j) { a[j] = b0[j]; a[4 + j] = b1[j]; }
#pragma unroll
        for (int dy = 0; dy < 3; ++dy) {
            int ny = y + dy - 1;
            if (ny < 0 || ny >= 28) continue;
#pragma unroll
            for (int dx = 0; dx < 3; ++dx) {
                int nx = xx + dx - 1;
                if (nx < 0 || nx >= 28) continue;
                v8bf xv = *(const v8bf*)&xin[(rowbase + ny * 28 + nx) * CDIM + c0];
                v8bf wv = *(const v8bf*)&wt[(dy * 3 + dx) * CDIM + c0];
#pragma unroll
                for (int j = 0; j < 8; ++j) a[j] += (float)xv[j] * (float)wv[j];
            }
        }
#pragma unroll
        for (int j = 0; j < 8; ++j) { v[j] = a[j]; sum += a[j]; sq += a[j] * a[j]; }
    }
    if (lane < 8) {
        const int c0 = 512 + lane * 8;
        float a[8];
        f32x4 b0 = *(const f32x4*)&bias2[c0];
        f32x4 b1 = *(const f32x4*)&bias2[c0 + 4];
#pragma unroll
        for (int j = 0; j < 4; ++j) { a[j] = b0[j]; a[4 + j] = b1[j]; }
#pragma unroll
        for (int dy = 0; dy < 3; ++dy) {
            int ny = y + dy - 1;
            if (ny < 0 || ny >= 28) continue;
#pragma unroll
            for (int dx = 0; dx < 3; ++dx) {
                int nx = xx + dx - 1;
                if (nx < 0 || nx >= 28) continue;
                v8bf xv = *(const v8bf*)&xin[(rowbase + ny * 28 + nx) * CDIM + c0];
                v8bf wv = *(const v8bf*)&wt[(dy * 3 + dx) * CDIM + c0];
#pragma unroll
                for (int j = 0; j < 8; ++j) a[j] += (float)xv[j] * (float)wv[j];
            }
        }
#pragma unroll
        for (int j = 0; j < 8; ++j) { v[8 + j] = a[j]; sum += a[j]; sq += a[j] * a[j]; }
    }

#pragma unroll
    for (int o = 32; o >= 1; o >>= 1) {
        sum += __shfl_xor(sum, o, 64);
        sq  += __shfl_xor(sq,  o, 64);
    }
    const float mean = sum * (1.0f / CDIM);
    const float rstd = rsqrtf(sq * (1.0f / CDIM) - mean * mean + 1e-5f);

    {
        const int c0 = lane * 8;
        v8bf o3, ol;
#pragma unroll
        for (int j = 0; j < 8; ++j) {
            o3[j] = (__bf16)v[j];
            ol[j] = (__bf16)((v[j] - mean) * rstd * g[c0 + j] + b[c0 + j]);
        }
        *(v8bf*)&x3[p * CDIM + c0]  = o3;
        *(v8bf*)&lnm[p * CDIM + c0] = ol;
    }
    if (lane < 8) {
        const int c0 = 512 + lane * 8;
        v8bf o3, ol;
#pragma unroll
        for (int j = 0; j < 8; ++j) {
            o3[j] = (__bf16)v[8 + j];
            ol[j] = (__bf16)((v[8 + j] - mean) * rstd * g[c0 + j] + b[c0 + j]);
        }
        *(v8bf*)&x3[p * CDIM + c0]  = o3;
        *(v8bf*)&lnm[p * CDIM + c0] = ol;
    }
}

extern "C" void kernel_launch(void* const* d_in, const int* in_sizes, int n_in,
                              void* d_out, int out_size, void* d_ws, size_t ws_size,
                              hipStream_t stream)
{
    (void)in_sizes; (void)n_in; (void)out_size; (void)ws_size;
    const float* x          = (const float*)d_in[0];
    const float* gamma_a    = (const float*)d_in[1];
    const float* beta_a     = (const float*)d_in[2];
    const float* qkv_w      = (const float*)d_in[3];
    const float* qkv_b      = (const float*)d_in[4];
    const float* proj_w     = (const float*)d_in[5];
    const float* proj_b     = (const float*)d_in[6];
    const float* attn_bias  = (const float*)d_in[7];
    const float* conv_w     = (const float*)d_in[8];
    const float* bn_g       = (const float*)d_in[9];
    const float* bn_b       = (const float*)d_in[10];
    const float* bn_m       = (const float*)d_in[11];
    const float* bn_v       = (const float*)d_in[12];
    const float* gamma_m    = (const float*)d_in[13];
    const float* beta_m     = (const float*)d_in[14];
    const float* fc1_w      = (const float*)d_in[15];
    const float* fc1_b      = (const float*)d_in[16];
    const float* fc2_w      = (const float*)d_in[17];
    const float* fc2_b      = (const float*)d_in[18];
    const int*   bidx       = (const int*)d_in[19];

    const size_t T = TOKENS;
    // ---- workspace layout (bf16 elems) — alias-audited per stage ----
    // [0,T*576)         hbuf (LN_a out) -> aout (attn out) -> lnm (conv_bn_ln out)
    // [T*576,T*2304)    qkvbuf -> (joins f1)
    // [T*2304,T*2880)   x2 (proj out) -> (tail of f1)
    // f1 = [T*576, T*2880)  (qkvbuf+x2, both dead at fc1; disjoint from lnm)
    // [T*2880,T*3456)   x3 (conv out, residual for fc2); weights after.
    __bf16* ws     = (__bf16*)d_ws;
    __bf16* hbuf   = ws;
    __bf16* qkvbuf = ws + T * 576;
    __bf16* aout   = ws;                 // reuse hbuf
    __bf16* x2     = ws + T * 2304;
    __bf16* x3     = ws + T * 2880;
    __bf16* lnm    = ws;                 // reuse hbuf/aout (dead after proj)
    __bf16* f1     = ws + T * 576;       // qkvbuf + x2 regions (dead at fc1)
    __bf16* wq     = x3 + T * 576;                   // qkv_w bf16  [1728*576]
    __bf16* wp     = wq + (size_t)QKVD * CDIM;       // proj_w bf16 [576*576]
    __bf16* w1     = wp + (size_t)CDIM * CDIM;       // fc1_w bf16  [2304*576]
    __bf16* w2     = w1 + (size_t)2304 * CDIM;       // fc2_w bf16  [576*2304]
    __bf16* wt     = w2 + (size_t)CDIM * 2304;       // conv wt [9][576]
    float*  bias2  = (float*)(wt + 9 * CDIM);        // conv bias [576]
    float*  outp   = (float*)d_out;

    // all 4 weight casts in one launch (dests contiguous starting at wq)
    cast4_kernel<<<dim3(3888), 256, 0, stream>>>(qkv_w, proj_w, fc1_w, fc2_w, wq);
    conv_prep<<<dim3(9), 64, 0, stream>>>(conv_w, bn_g, bn_b, bn_m, bn_v, wt, bias2);

    ln_kernel<<<dim3(T / 4), 256, 0, stream>>>(x, gamma_a, beta_a, hbuf);
    gemm_bt<0, __bf16, float><<<dim3(196 * 9), 512, 0, stream>>>(
        hbuf, wq, qkv_b, nullptr, qkvbuf, QKVD, CDIM, 9);
    attn_kernel<<<dim3(NHEAD, 1024), 64, 0, stream>>>(qkvbuf, attn_bias, bidx, aout);
    gemm_bt<1, __bf16, float><<<dim3(196 * 3), 512, 0, stream>>>(
        aout, wp, proj_b, x, x2, CDIM, CDIM, 3);
    conv_bn_ln<<<dim3(12544), 256, 0, stream>>>(x2, wt, bias2, gamma_m, beta_m,
                                                x3, lnm);
    gemm_bt2<<<dim3(392 * 12), 256, 0, stream>>>(
        lnm, w1, fc1_b, f1, 2304, CDIM, 12);
    gemm_bt<1, float, __bf16><<<dim3(196 * 3), 512, 0, stream>>>(
        f1, w2, fc2_b, x3, outp, CDIM, 2304, 3);
}